// Round 1
// baseline (626.559 us; speedup 1.0000x reference)
//
#include <hip/hip_runtime.h>
#include <stdint.h>

#define NCLS    80
#define NA_TOT  8400     // 6400 + 1600 + 400
#define NBATCH  32
#define MAXDET  300
#define SORTN   16384
#define CONFTHR 0.001f

// ---------------------------------------------------------------------------
// Bit-exact reconstruction of XLA:CPU f32 exp (llvm_ir_runtime GenerateVF32Exp,
// Eigen/Cephes pexp, no FMA contraction) and logistic = 1/(1+exp(-x)).
// All ops via __f*_rn intrinsics so -ffp-contract=fast cannot fuse them.
// ---------------------------------------------------------------------------
__device__ __forceinline__ float xla_expf(float in) {
  const float exp_hi = 88.3762626647950f;
  const float exp_lo = -88.3762626647949f;
  const float LOG2EF = 1.44269504088896341f;
  const float C1 = 0.693359375f;
  const float C2 = -2.12194440e-4f;
  const float p0 = 1.9875691500E-4f, p1 = 1.3981999507E-3f, p2 = 8.3334519073E-3f;
  const float p3 = 4.1665795894E-2f, p4 = 1.6666665459E-1f, p5 = 5.0000001201E-1f;
  float x = fminf(fmaxf(in, exp_lo), exp_hi);
  float fx = floorf(__fadd_rn(__fmul_rn(x, LOG2EF), 0.5f));
  float tmp = __fmul_rn(C1, fx);
  float z   = __fmul_rn(C2, fx);
  x = __fsub_rn(x, tmp);
  x = __fsub_rn(x, z);
  float y = __fadd_rn(__fmul_rn(x, p0), p1);
  y = __fadd_rn(__fmul_rn(y, x), p2);
  y = __fadd_rn(__fmul_rn(y, x), p3);
  y = __fadd_rn(__fmul_rn(y, x), p4);
  y = __fadd_rn(__fmul_rn(y, x), p5);
  y = __fadd_rn(__fmul_rn(y, __fmul_rn(x, x)), x);
  y = __fadd_rn(1.0f, y);
  int m = (int)fx;                       // FPToSI (fx is integral after floor)
  float s = __uint_as_float((uint32_t)(m + 127) << 23);
  float r = __fmul_rn(y, s);
  return fmaxf(r, in);                   // XLA emits Max(result, input)
}

__device__ __forceinline__ float xla_sigmoid(float v) {
  float e = xla_expf(-v);
  float den = __fadd_rn(1.0f, e);
  return 1.0f / den;                     // IEEE-correct fdiv (no fast-math)
}

// ---------------------------------------------------------------------------
// Kernel 1: DFL decode + class max/argmax, per (batch, anchor).
// ---------------------------------------------------------------------------
__global__ __launch_bounds__(256) void yolo_decode_kernel(
    const float* __restrict__ f0, const float* __restrict__ f1,
    const float* __restrict__ f2,
    float4* __restrict__ oboxes, float* __restrict__ oconf,
    float* __restrict__ oclsf) {
  int t = blockIdx.x * 256 + threadIdx.x;
  if (t >= NBATCH * NA_TOT) return;
  int b = t / NA_TOT;
  int a = t - b * NA_TOT;

  const float* base; int ai, W; float stridef;
  if (a < 6400)      { base = f0 + (size_t)b * (144 * 6400); ai = a;        W = 80; stridef = 8.0f;  }
  else if (a < 8000) { base = f1 + (size_t)b * (144 * 1600); ai = a - 6400; W = 40; stridef = 16.0f; }
  else               { base = f2 + (size_t)b * (144 * 400);  ai = a - 8000; W = 20; stridef = 32.0f; }
  int Alvl = W * W;
  const float* cptr = base + ai;
  float ax = __fadd_rn((float)(ai % W), 0.5f);
  float ay = __fadd_rn((float)(ai / W), 0.5f);

  // DFL softmax-expectation for each of the 4 sides (16 bins each)
  float ltrb[4];
  #pragma unroll
  for (int fs = 0; fs < 4; ++fs) {
    float d[16];
    float mx = -INFINITY;
    #pragma unroll
    for (int r = 0; r < 16; ++r) {
      d[r] = cptr[(size_t)(fs * 16 + r) * Alvl];
      mx = fmaxf(mx, d[r]);
    }
    float e[16];
    float ssum = 0.0f;
    #pragma unroll
    for (int r = 0; r < 16; ++r) {
      e[r] = xla_expf(__fsub_rn(d[r], mx));
      ssum = __fadd_rn(ssum, e[r]);
    }
    float acc = 0.0f;
    #pragma unroll
    for (int r = 0; r < 16; ++r) {
      float p = e[r] / ssum;                       // softmax = unnorm / sum
      acc = __fadd_rn(acc, __fmul_rn(p, (float)r)); // einsum with proj
    }
    ltrb[fs] = acc;
  }

  float x1 = __fsub_rn(ax, ltrb[0]);
  float y1 = __fsub_rn(ay, ltrb[1]);
  float x2 = __fadd_rn(ax, ltrb[2]);
  float y2 = __fadd_rn(ay, ltrb[3]);
  float cx = __fmul_rn(__fadd_rn(x1, x2), 0.5f);
  float cy = __fmul_rn(__fadd_rn(y1, y2), 0.5f);
  float w  = __fsub_rn(x2, x1);
  float h  = __fsub_rn(y2, y1);
  float4 box = make_float4(__fmul_rn(cx, stridef), __fmul_rn(cy, stridef),
                           __fmul_rn(w, stridef),  __fmul_rn(h, stridef));

  // conf = max over sigmoid(cls logits), argmax = first max (strict >)
  float best = -INFINITY;
  int bi = 0;
  for (int k = 0; k < NCLS; ++k) {
    float v = cptr[(size_t)(64 + k) * Alvl];
    float s = xla_sigmoid(v);
    if (s > best) { best = s; bi = k; }
  }
  float conf = (best > CONFTHR) ? best : 0.0f;

  oboxes[t] = box;
  oconf[t]  = conf;
  oclsf[t]  = (float)bi;
}

// ---------------------------------------------------------------------------
// Kernel 2: per-image (one block, 1024 threads):
//   bitonic sort of 64-bit keys (conf_bits<<32 | (0xFFFFFFFF - anchor))
//   -> exact lax.top_k stable-descending order, then greedy NMS walk
//      (equivalent to the reference 300-step argmax scan).
// ---------------------------------------------------------------------------
__global__ __launch_bounds__(1024) void yolo_sortnms_kernel(
    const float4* __restrict__ boxes, const float* __restrict__ conf,
    const float* __restrict__ clsf, float* __restrict__ out) {
  __shared__ unsigned long long keys[SORTN];   // 128 KiB
  __shared__ unsigned long long amask[16];
  int b   = blockIdx.x;
  int tid = threadIdx.x;
  int wid = tid >> 6, lane = tid & 63;

  // load keys (pad with 0 => sorts to bottom)
  for (int i = tid; i < SORTN; i += 1024) {
    unsigned long long kk = 0ull;
    if (i < NA_TOT) {
      unsigned cb = __float_as_uint(conf[b * NA_TOT + i]);  // conf >= 0
      kk = ((unsigned long long)cb << 32) |
           (unsigned long long)(0xFFFFFFFFu - (unsigned)i); // tie: low idx wins
    }
    keys[i] = kk;
  }
  __syncthreads();

  // bitonic sort ascending (top candidates end up at the back)
  for (int k = 2; k <= SORTN; k <<= 1) {
    for (int j = k >> 1; j > 0; j >>= 1) {
      for (int wq = tid; wq < SORTN / 2; wq += 1024) {
        int i = ((wq & ~(j - 1)) << 1) | (wq & (j - 1));
        int l = i | j;
        unsigned long long A = keys[i], B = keys[l];
        bool up = ((i & k) == 0);
        if (up ? (A > B) : (A < B)) { keys[i] = B; keys[l] = A; }
      }
      __syncthreads();
    }
  }

  // gather: thread tid owns sorted rank tid (descending)
  unsigned long long key = keys[SORTN - 1 - tid];
  float  myconf = __uint_as_float((unsigned)(key >> 32));
  float4 mycb = make_float4(0.f, 0.f, 0.f, 0.f);
  float4 mybx = make_float4(0.f, 0.f, 0.f, 0.f);
  float  mycls = 0.0f;
  bool   alive = false;
  if (myconf > CONFTHR) {
    unsigned a = 0xFFFFFFFFu - (unsigned)(key & 0xFFFFFFFFull);
    mycb  = boxes[b * NA_TOT + a];
    mycls = clsf[b * NA_TOT + a];
    float off = __fmul_rn(mycls, 7680.0f);
    float hw = __fmul_rn(mycb.z, 0.5f);
    float hh = __fmul_rn(mycb.w, 0.5f);
    mybx.x = __fadd_rn(__fsub_rn(mycb.x, hw), off);
    mybx.y = __fadd_rn(__fsub_rn(mycb.y, hh), off);
    mybx.z = __fadd_rn(__fadd_rn(mycb.x, hw), off);
    mybx.w = __fadd_rn(__fadd_rn(mycb.y, hh), off);
    alive = true;
  }
  __syncthreads();   // all key reads done before aliasing LDS as box array

  float4* bxl = reinterpret_cast<float4*>(keys);  // 1024 * 16B reuse
  bxl[tid] = mybx;

  float* orow = out + (size_t)b * (MAXDET * 6);
  for (int e = 0; e < MAXDET; ++e) {
    unsigned long long bal = __ballot(alive ? 1 : 0);
    if (lane == 0) amask[wid] = bal;
    __syncthreads();          // covers bxl writes on first iteration too

    int pos = -1;
    #pragma unroll
    for (int wq = 0; wq < 16; ++wq) {
      unsigned long long m = amask[wq];
      if (pos < 0 && m) pos = wq * 64 + (__ffsll(m) - 1);
    }
    if (pos < 0) break;       // uniform decision (same amask view)

    float4 wbx = bxl[pos];    // LDS broadcast read
    if (tid == pos) {
      orow[e * 6 + 0] = mycb.x;
      orow[e * 6 + 1] = mycb.y;
      orow[e * 6 + 2] = mycb.z;
      orow[e * 6 + 3] = mycb.w;
      orow[e * 6 + 4] = myconf;
      orow[e * 6 + 5] = mycls;
    }
    if (alive) {
      // exact reference IoU: inter / (a1 + a2 - inter + 1e-7) > 0.7
      float ltx = fmaxf(wbx.x, mybx.x);
      float lty = fmaxf(wbx.y, mybx.y);
      float rbx = fminf(wbx.z, mybx.z);
      float rby = fminf(wbx.w, mybx.w);
      float iw = fmaxf(__fsub_rn(rbx, ltx), 0.0f);
      float ih = fmaxf(__fsub_rn(rby, lty), 0.0f);
      float inter = __fmul_rn(iw, ih);
      float a1 = __fmul_rn(__fsub_rn(wbx.z, wbx.x), __fsub_rn(wbx.w, wbx.y));
      float a2 = __fmul_rn(__fsub_rn(mybx.z, mybx.x), __fsub_rn(mybx.w, mybx.y));
      float den = __fadd_rn(__fsub_rn(__fadd_rn(a1, a2), inter), 1e-7f);
      float iou = inter / den;
      if (iou > 0.7f) alive = false;   // winner self-suppresses (iou ~= 1)
    }
    __syncthreads();          // amask reused next iteration
  }
}

extern "C" void kernel_launch(void* const* d_in, const int* in_sizes, int n_in,
                              void* d_out, int out_size, void* d_ws, size_t ws_size,
                              hipStream_t stream) {
  const float* f0 = (const float*)d_in[0];
  const float* f1 = (const float*)d_in[1];
  const float* f2 = (const float*)d_in[2];
  float* out = (float*)d_out;

  char* ws = (char*)d_ws;
  float4* boxes = (float4*)ws;                                   // 32*8400*16 B
  float*  conf  = (float*)(ws + (size_t)NBATCH * NA_TOT * 16);   // 32*8400*4 B
  float*  clsf  = (float*)(ws + (size_t)NBATCH * NA_TOT * 20);   // 32*8400*4 B

  hipMemsetAsync(d_out, 0, (size_t)out_size * sizeof(float), stream);

  int tot = NBATCH * NA_TOT;
  yolo_decode_kernel<<<(tot + 255) / 256, 256, 0, stream>>>(f0, f1, f2,
                                                            boxes, conf, clsf);
  yolo_sortnms_kernel<<<NBATCH, 1024, 0, stream>>>(boxes, conf, clsf, out);
}

// Round 2
// 203.319 us; speedup vs baseline: 3.0816x; 3.0816x over previous
//
#include <hip/hip_runtime.h>
#include <stdint.h>

#define NCLS    80
#define NA_TOT  8400     // 6400 + 1600 + 400
#define NBATCH  32
#define MAXDET  300
#define SSORT   2048
#define CONFTHR 0.001f

// ---------------------------------------------------------------------------
// Bit-exact reconstruction of XLA:CPU f32 exp (Eigen/Cephes pexp, no FMA) and
// logistic = 1/(1+exp(-x)). Validated absmax==0.0 in round 1. DO NOT TOUCH.
// ---------------------------------------------------------------------------
__device__ __forceinline__ float xla_expf(float in) {
  const float exp_hi = 88.3762626647950f;
  const float exp_lo = -88.3762626647949f;
  const float LOG2EF = 1.44269504088896341f;
  const float C1 = 0.693359375f;
  const float C2 = -2.12194440e-4f;
  const float p0 = 1.9875691500E-4f, p1 = 1.3981999507E-3f, p2 = 8.3334519073E-3f;
  const float p3 = 4.1665795894E-2f, p4 = 1.6666665459E-1f, p5 = 5.0000001201E-1f;
  float x = fminf(fmaxf(in, exp_lo), exp_hi);
  float fx = floorf(__fadd_rn(__fmul_rn(x, LOG2EF), 0.5f));
  float tmp = __fmul_rn(C1, fx);
  float z   = __fmul_rn(C2, fx);
  x = __fsub_rn(x, tmp);
  x = __fsub_rn(x, z);
  float y = __fadd_rn(__fmul_rn(x, p0), p1);
  y = __fadd_rn(__fmul_rn(y, x), p2);
  y = __fadd_rn(__fmul_rn(y, x), p3);
  y = __fadd_rn(__fmul_rn(y, x), p4);
  y = __fadd_rn(__fmul_rn(y, x), p5);
  y = __fadd_rn(__fmul_rn(y, __fmul_rn(x, x)), x);
  y = __fadd_rn(1.0f, y);
  int m = (int)fx;
  float s = __uint_as_float((uint32_t)(m + 127) << 23);
  float r = __fmul_rn(y, s);
  return fmaxf(r, in);
}

__device__ __forceinline__ float xla_sigmoid(float v) {
  float e = xla_expf(-v);
  float den = __fadd_rn(1.0f, e);
  return 1.0f / den;
}

// ---------------------------------------------------------------------------
// Kernel 1: DFL decode + class max/argmax, per (batch, anchor). Unchanged.
// ---------------------------------------------------------------------------
__global__ __launch_bounds__(256) void yolo_decode_kernel(
    const float* __restrict__ f0, const float* __restrict__ f1,
    const float* __restrict__ f2,
    float4* __restrict__ oboxes, float* __restrict__ oconf,
    float* __restrict__ oclsf) {
  int t = blockIdx.x * 256 + threadIdx.x;
  if (t >= NBATCH * NA_TOT) return;
  int b = t / NA_TOT;
  int a = t - b * NA_TOT;

  const float* base; int ai, W; float stridef;
  if (a < 6400)      { base = f0 + (size_t)b * (144 * 6400); ai = a;        W = 80; stridef = 8.0f;  }
  else if (a < 8000) { base = f1 + (size_t)b * (144 * 1600); ai = a - 6400; W = 40; stridef = 16.0f; }
  else               { base = f2 + (size_t)b * (144 * 400);  ai = a - 8000; W = 20; stridef = 32.0f; }
  int Alvl = W * W;
  const float* cptr = base + ai;
  float ax = __fadd_rn((float)(ai % W), 0.5f);
  float ay = __fadd_rn((float)(ai / W), 0.5f);

  float ltrb[4];
  #pragma unroll
  for (int fs = 0; fs < 4; ++fs) {
    float d[16];
    float mx = -INFINITY;
    #pragma unroll
    for (int r = 0; r < 16; ++r) {
      d[r] = cptr[(size_t)(fs * 16 + r) * Alvl];
      mx = fmaxf(mx, d[r]);
    }
    float e[16];
    float ssum = 0.0f;
    #pragma unroll
    for (int r = 0; r < 16; ++r) {
      e[r] = xla_expf(__fsub_rn(d[r], mx));
      ssum = __fadd_rn(ssum, e[r]);
    }
    float acc = 0.0f;
    #pragma unroll
    for (int r = 0; r < 16; ++r) {
      float p = e[r] / ssum;
      acc = __fadd_rn(acc, __fmul_rn(p, (float)r));
    }
    ltrb[fs] = acc;
  }

  float x1 = __fsub_rn(ax, ltrb[0]);
  float y1 = __fsub_rn(ay, ltrb[1]);
  float x2 = __fadd_rn(ax, ltrb[2]);
  float y2 = __fadd_rn(ay, ltrb[3]);
  float cx = __fmul_rn(__fadd_rn(x1, x2), 0.5f);
  float cy = __fmul_rn(__fadd_rn(y1, y2), 0.5f);
  float w  = __fsub_rn(x2, x1);
  float h  = __fsub_rn(y2, y1);
  float4 box = make_float4(__fmul_rn(cx, stridef), __fmul_rn(cy, stridef),
                           __fmul_rn(w, stridef),  __fmul_rn(h, stridef));

  float best = -INFINITY;
  int bi = 0;
  for (int k = 0; k < NCLS; ++k) {
    float v = cptr[(size_t)(64 + k) * Alvl];
    float s = xla_sigmoid(v);
    if (s > best) { best = s; bi = k; }
  }
  float conf = (best > CONFTHR) ? best : 0.0f;

  oboxes[t] = box;
  oconf[t]  = conf;
  oclsf[t]  = (float)bi;
}

// ---------------------------------------------------------------------------
// Kernel 2: per-image select (histogram radix-descent) + sort-2048 + NMS
//   (class-list suppression-bit rows + single-wave ffs walk).
// ---------------------------------------------------------------------------
struct LdsA {                       // selection/sort phase (~66.4 KB)
  unsigned confL[NA_TOT];           // 33600 B
  unsigned hist[2048];              //  8192 B
  unsigned Tarr[2049];              //  8196 B
  unsigned long long sortkeys[SSORT]; // 16384 B
};
struct LdsB {                       // NMS phase (~157 KB)
  unsigned long long rows[1024][16];  // 131072 B  (overlaps all of LdsA)
  float    rowdata[1024][6];          //  24576 B  (beyond LdsA: no overlap)
  unsigned list[1024];                //   4096 B
  unsigned clsCnt[NCLS];              //    320 B
  unsigned clsBase[NCLS];             //    320 B
  unsigned clsCur[NCLS];              //    320 B
  unsigned long long alive[16];       //    128 B
};

__global__ __launch_bounds__(1024) void yolo_selectnms_kernel(
    const float4* __restrict__ boxes, const float* __restrict__ conf,
    const float* __restrict__ clsf, float* __restrict__ out) {
  __shared__ union { LdsA a; LdsB b; } u;
  __shared__ unsigned s_need, s_prefix, s_found, s_B, s_scnt, s_cut;
  int b   = blockIdx.x;
  int tid = threadIdx.x;
  const unsigned* confu = (const unsigned*)conf + (size_t)b * NA_TOT;

  // ---- S1: stage conf bits; zero B-tail state (beyond LdsA, safe) ----
  for (int i = tid; i < NA_TOT; i += 1024) u.a.confL[i] = confu[i];
  if (tid < NCLS) u.b.clsCnt[tid] = 0;
  if (tid < 16)   u.b.alive[tid]  = 0ull;
  if (tid == 0) { s_need = 1024; s_prefix = 0; s_cut = 0; }
  __syncthreads();

  // ---- S2: 3-level radix descent to exact 1024th-largest conf bits ----
  for (int lv = 0; lv < 3; ++lv) {
    for (int i = tid; i < 2048; i += 1024) u.a.hist[i] = 0;
    if (tid == 0) { s_found = 0; s_B = 0; }
    __syncthreads();
    unsigned pfx = s_prefix;
    for (int i = tid; i < NA_TOT; i += 1024) {
      unsigned c = u.a.confL[i];
      if (c == 0) continue;
      bool in; unsigned bin;
      if (lv == 0)      { in = true;               bin = c >> 21; }
      else if (lv == 1) { in = ((c >> 21) == pfx); bin = (c >> 10) & 0x7FF; }
      else              { in = ((c >> 10) == pfx); bin = c & 0x3FF; }
      if (in) atomicAdd(&u.a.hist[bin], 1u);
    }
    __syncthreads();
    if (tid < 64) {                       // wave-0 suffix scan (from top)
      unsigned carry = 0;
      if (tid == 0) u.a.Tarr[2048] = 0;
      for (int ch = 31; ch >= 0; --ch) {
        int bb = ch * 64 + tid;
        unsigned v = u.a.hist[bb];
        #pragma unroll
        for (int off = 1; off < 64; off <<= 1) {
          unsigned t = __shfl_down(v, off);
          if (tid + off < 64) v += t;
        }
        u.a.Tarr[bb] = v + carry;
        carry += __shfl(v, 0);            // lane0 holds chunk total
      }
    }
    __syncthreads();
    unsigned need = s_need;
    for (int i = tid; i < 2048; i += 1024) {
      unsigned h = u.a.hist[i];
      if (h > 0 && u.a.Tarr[i + 1] < need && u.a.Tarr[i + 1] + h >= need) {
        s_B = (unsigned)i; s_found = 1;   // unique writer (proof: T monotone)
      }
    }
    __syncthreads();
    if (!s_found) {                       // shortage: descend to min element
      unsigned tot = u.a.Tarr[0];
      for (int i = tid; i < 2048; i += 1024) {
        unsigned h = u.a.hist[i];
        if (h > 0 && u.a.Tarr[i] == tot) s_B = (unsigned)i;  // smallest nonempty
      }
    }
    __syncthreads();
    if (tid == 0) {
      unsigned B = s_B;
      s_need = s_need - u.a.Tarr[B + 1];
      if (lv == 0)      s_prefix = B;
      else if (lv == 1) s_prefix = (s_prefix << 11) | B;
      else              s_cut    = (s_prefix << 10) | B;
    }
    __syncthreads();
  }

  // ---- S3: compact selected (c >= cut, c != 0) then pad + bitonic sort ----
  if (tid == 0) s_scnt = 0;
  __syncthreads();
  unsigned cut = s_cut;
  for (int i = tid; i < NA_TOT; i += 1024) {
    unsigned c = u.a.confL[i];
    if (c != 0 && c >= cut) {
      unsigned p = atomicAdd(&s_scnt, 1u);
      if (p < SSORT)
        u.a.sortkeys[p] = ((unsigned long long)c << 32) |
                          (unsigned long long)(0xFFFFFFFFu - (unsigned)i);
    }
  }
  __syncthreads();
  unsigned scnt = s_scnt;
  for (int p = tid; p < SSORT; p += 1024)
    if (p >= scnt) u.a.sortkeys[p] = 0ull;
  __syncthreads();

  for (int k = 2; k <= SSORT; k <<= 1) {
    for (int j = k >> 1; j > 0; j >>= 1) {
      int i = ((tid & ~(j - 1)) << 1) | (tid & (j - 1));
      int l = i | j;
      unsigned long long A = u.a.sortkeys[i], Bv = u.a.sortkeys[l];
      bool up = ((i & k) == 0);
      if (up ? (A > Bv) : (A < Bv)) { u.a.sortkeys[i] = Bv; u.a.sortkeys[l] = A; }
      __syncthreads();
    }
  }

  // ---- S4: rank setup (reads sortkeys[A]; writes only beyond-A B fields) ----
  unsigned long long key = u.a.sortkeys[SSORT - 1 - tid];  // rank tid, descending
  bool valid = (key >> 32) != 0ull;
  float4 cb = make_float4(0.f, 0.f, 0.f, 0.f);
  float cls = 0.f, cf = 0.f;
  if (valid) {
    cf = __uint_as_float((unsigned)(key >> 32));
    unsigned a = 0xFFFFFFFFu - (unsigned)(key & 0xFFFFFFFFull);
    cb  = boxes[(size_t)b * NA_TOT + a];
    cls = clsf[(size_t)b * NA_TOT + a];
  }
  u.b.rowdata[tid][0] = cb.x;
  u.b.rowdata[tid][1] = cb.y;
  u.b.rowdata[tid][2] = cb.z;
  u.b.rowdata[tid][3] = cb.w;
  u.b.rowdata[tid][4] = cf;
  u.b.rowdata[tid][5] = cls;
  if (valid) {
    atomicOr(&u.b.alive[tid >> 6], 1ull << (tid & 63));
    atomicAdd(&u.b.clsCnt[(int)cls], 1u);
  }
  __syncthreads();        // sortkeys dead from here; rows region reusable

  // ---- S5: zero rows; build per-class candidate lists ----
  #pragma unroll
  for (int q = 0; q < 16; ++q) u.b.rows[tid][q] = 0ull;
  if (tid == 0) {
    unsigned acc = 0;
    for (int c2 = 0; c2 < NCLS; ++c2) {
      u.b.clsBase[c2] = acc; u.b.clsCur[c2] = acc; acc += u.b.clsCnt[c2];
    }
  }
  __syncthreads();
  if (valid) {
    unsigned p = atomicAdd(&u.b.clsCur[(int)cls], 1u);
    u.b.list[p] = (unsigned)tid;
  }
  __syncthreads();

  // ---- S6: suppression-bit rows (same-class pairs only; ~13/class avg) ----
  if (valid) {
    int c = (int)cls;
    unsigned base = u.b.clsBase[c], cnt = u.b.clsCnt[c];
    float off = __fmul_rn(cls, 7680.0f);
    float hw  = __fmul_rn(cb.z, 0.5f), hh = __fmul_rn(cb.w, 0.5f);
    float wx1 = __fadd_rn(__fsub_rn(cb.x, hw), off);
    float wy1 = __fadd_rn(__fsub_rn(cb.y, hh), off);
    float wx2 = __fadd_rn(__fadd_rn(cb.x, hw), off);
    float wy2 = __fadd_rn(__fadd_rn(cb.y, hh), off);
    float a1  = __fmul_rn(__fsub_rn(wx2, wx1), __fsub_rn(wy2, wy1)); // winner area
    for (unsigned l = 0; l < cnt; ++l) {
      int j = (int)u.b.list[base + l];
      float jx = u.b.rowdata[j][0], jy = u.b.rowdata[j][1];
      float jw = u.b.rowdata[j][2], jh = u.b.rowdata[j][3];
      float jhw = __fmul_rn(jw, 0.5f), jhh = __fmul_rn(jh, 0.5f);
      float jx1 = __fadd_rn(__fsub_rn(jx, jhw), off);
      float jy1 = __fadd_rn(__fsub_rn(jy, jhh), off);
      float jx2 = __fadd_rn(__fadd_rn(jx, jhw), off);
      float jy2 = __fadd_rn(__fadd_rn(jy, jhh), off);
      float ltx = fmaxf(wx1, jx1), lty = fmaxf(wy1, jy1);
      float rbx = fminf(wx2, jx2), rby = fminf(wy2, jy2);
      float iw = fmaxf(__fsub_rn(rbx, ltx), 0.0f);
      float ih = fmaxf(__fsub_rn(rby, lty), 0.0f);
      float inter = __fmul_rn(iw, ih);
      float a2 = __fmul_rn(__fsub_rn(jx2, jx1), __fsub_rn(jy2, jy1));
      float den = __fadd_rn(__fsub_rn(__fadd_rn(a1, a2), inter), 1e-7f);
      float iou = inter / den;
      if (iou > 0.7f)
        u.b.rows[tid][j >> 6] |= (1ull << (j & 63));
    }
  }
  __syncthreads();

  // ---- S7: single-wave greedy walk (no barriers; ffs over alive mask) ----
  if (tid < 64) {
    int lane = tid;
    unsigned long long am = (lane < 16) ? u.b.alive[lane] : 0ull;
    float* orow = out + (size_t)b * (MAXDET * 6);
    int e = 0;
    while (e < MAXDET) {
      unsigned long long bal = __ballot(am != 0ull);
      if (bal == 0ull) break;
      int f    = __ffsll((unsigned long long)bal) - 1;  // first lane w/ alive
      int myb  = __ffsll((unsigned long long)am) - 1;   // -1 on empty lanes ok
      int bitp = __shfl(myb, f);
      int r    = f * 64 + bitp;                         // winner rank
      if (lane < 6) orow[e * 6 + lane] = u.b.rowdata[r][lane];
      unsigned long long rowv = (lane < 16) ? u.b.rows[r][lane] : 0ull;
      am &= ~rowv;     // winner self-suppresses iff its self-IoU > 0.7,
      ++e;             // exactly matching the reference scan semantics
    }
  }
}

extern "C" void kernel_launch(void* const* d_in, const int* in_sizes, int n_in,
                              void* d_out, int out_size, void* d_ws, size_t ws_size,
                              hipStream_t stream) {
  const float* f0 = (const float*)d_in[0];
  const float* f1 = (const float*)d_in[1];
  const float* f2 = (const float*)d_in[2];
  float* out = (float*)d_out;

  char* ws = (char*)d_ws;
  float4* boxes = (float4*)ws;                                   // 32*8400*16 B
  float*  conf  = (float*)(ws + (size_t)NBATCH * NA_TOT * 16);   // 32*8400*4 B
  float*  clsf  = (float*)(ws + (size_t)NBATCH * NA_TOT * 20);   // 32*8400*4 B

  hipMemsetAsync(d_out, 0, (size_t)out_size * sizeof(float), stream);

  int tot = NBATCH * NA_TOT;
  yolo_decode_kernel<<<(tot + 255) / 256, 256, 0, stream>>>(f0, f1, f2,
                                                            boxes, conf, clsf);
  yolo_selectnms_kernel<<<NBATCH, 1024, 0, stream>>>(boxes, conf, clsf, out);
}